// Round 4
// baseline (843.303 us; speedup 1.0000x reference)
//
#include <hip/hip_runtime.h>

// LIF layer: I = spikes @ W^T + b (fp32), then sequential fp32 LIF scan.
//
// NUMERICS CONTRACT (proven in round 2, absmax=0): each output element of the
// GEMM must be a strictly sequential ascending-k fmaf chain from 0.0f over
// k=0..1023, followed by exactly one fp32 bias add. The scan must be the exact
// op sequence t=v/20 (IEEE div); u=I-t; v=v+u; s=(v>1); v=s?0:v.
// Any blocking change must preserve the per-element rounding sequence.
//
// Round 4 perf change: round 3 was LDS-delivery-bound (8x8 micro-tile =
// 1.0 B LDS per FMA vs CU balance of 0.66-1.0; VALUBusy 69%) with 4-way
// bank aliasing on the W-fragment reads (6.55e7 conflict cycles). Now:
//  - 16x8 micro-tile (BM=256,BN=128,BK=32) -> 0.75 B/FMA
//  - W stored with chunk permutation perm(c)=c^(c>>2) per k-row so both
//    the ds_read_b128 fragment reads and the staging writes are <=2-way
//    (2-way is free per HW measurement); A reads are 16-lane broadcasts.
//  - k remains strictly ascending per element (contract intact).

constexpr int kT   = 100;
constexpr int kB   = 256;
constexpr int kIn  = 1024;
constexpr int kOut = 1024;
constexpr int kM   = kT * kB;          // 25600 GEMM rows

constexpr int BM = 256;
constexpr int BN = 128;
constexpr int BK = 32;

// ---------------------------------------------------------------------------
// GEMM: I[M,kOut] = A[M,kIn] * W^T[kOut,kIn] + bias   (fp32, sequential-k FMA)
// ---------------------------------------------------------------------------
__global__ __launch_bounds__(256, 2)
void gemm_f32(const float* __restrict__ A,
              const float* __restrict__ W,
              const float* __restrict__ bias,
              float* __restrict__ I)
{
    __shared__ float As[BK * BM];   // k-major: As[k*BM + m], linear
    __shared__ float Ws[BK * BN];   // k-major, 16B-chunk-permuted within row

    const int tid = threadIdx.x;
    const int m0  = blockIdx.y * BM;
    const int n0  = blockIdx.x * BN;

    // compute mapping: 16x16 thread grid; thread owns rows tr*16..+15,
    // cols tc*8..+7. Wave = tr 0..3 x tc 0..15.
    const int tc = tid & 15;
    const int tr = tid >> 4;

    // W-fragment read slots (chunk c stored at c^(c>>2); 4 floats per chunk)
    const int pw0 = (((2 * tc)     ) ^ ((2 * tc)     >> 2)) * 4;
    const int pw1 = (((2 * tc + 1) ) ^ ((2 * tc + 1) >> 2)) * 4;

    // staging mapping:
    //  A: thread stages global row (m0+tid), all BK k's  -> 8 float4
    //  W: thread stages global row (n0+tid/2), k-half (tid&1)*16 -> 4 float4
    const float* Arow = A + (size_t)(m0 + tid) * kIn;
    const int    wn   = tid >> 1;
    const int    wk0  = (tid & 1) * 16;
    const float* Wrow = W + (size_t)(n0 + wn) * kIn + wk0;
    const int    wslot = ((wn >> 2) ^ (wn >> 4)) * 4 + (wn & 3); // perm(n>>2)*4 + n%4

    float4 la[8], lw[4];
#pragma unroll
    for (int i = 0; i < 8; ++i)
        la[i] = *reinterpret_cast<const float4*>(Arow + i * 4);
#pragma unroll
    for (int i = 0; i < 4; ++i)
        lw[i] = *reinterpret_cast<const float4*>(Wrow + i * 4);

    float acc[16][8];
#pragma unroll
    for (int j = 0; j < 16; ++j)
#pragma unroll
        for (int l = 0; l < 8; ++l) acc[j][l] = 0.0f;

    for (int k0 = 0; k0 < kIn; k0 += BK) {
        __syncthreads();   // previous tile's compute done; LDS safe to overwrite

        // A writes: fixed k, lanes write 64 consecutive m -> 2-way (free)
#pragma unroll
        for (int i = 0; i < 8; ++i) {
            const float* p = reinterpret_cast<const float*>(&la[i]);
#pragma unroll
            for (int j = 0; j < 4; ++j)
                As[(i * 4 + j) * BM + tid] = p[j];
        }
        // W writes: permuted slots cover all 32 banks per 32 lanes -> 2-way
#pragma unroll
        for (int i = 0; i < 4; ++i) {
            const float* p = reinterpret_cast<const float*>(&lw[i]);
#pragma unroll
            for (int j = 0; j < 4; ++j)
                Ws[(wk0 + i * 4 + j) * BN + wslot] = p[j];
        }

        __syncthreads();

        // issue next tile's global loads; they drain under the FMA phase
        if (k0 + BK < kIn) {
            const int kn = k0 + BK;
#pragma unroll
            for (int i = 0; i < 8; ++i)
                la[i] = *reinterpret_cast<const float4*>(Arow + kn + i * 4);
#pragma unroll
            for (int i = 0; i < 4; ++i)
                lw[i] = *reinterpret_cast<const float4*>(Wrow + kn + i * 4);
        }

        // FMA phase: per k, 4 broadcast A-reads + 2 permuted W-reads + 128 fmaf.
        // k strictly ascending => per-element chain order preserved.
#pragma unroll 4
        for (int k = 0; k < BK; ++k) {
            const float4 a0 = *reinterpret_cast<const float4*>(&As[k * BM + tr * 16 +  0]);
            const float4 a1 = *reinterpret_cast<const float4*>(&As[k * BM + tr * 16 +  4]);
            const float4 a2 = *reinterpret_cast<const float4*>(&As[k * BM + tr * 16 +  8]);
            const float4 a3 = *reinterpret_cast<const float4*>(&As[k * BM + tr * 16 + 12]);
            const float4 w0 = *reinterpret_cast<const float4*>(&Ws[k * BN + pw0]);
            const float4 w1 = *reinterpret_cast<const float4*>(&Ws[k * BN + pw1]);
            const float a[16] = {a0.x, a0.y, a0.z, a0.w, a1.x, a1.y, a1.z, a1.w,
                                 a2.x, a2.y, a2.z, a2.w, a3.x, a3.y, a3.z, a3.w};
            const float w[8]  = {w0.x, w0.y, w0.z, w0.w, w1.x, w1.y, w1.z, w1.w};
#pragma unroll
            for (int j = 0; j < 16; ++j)
#pragma unroll
                for (int l = 0; l < 8; ++l)
                    acc[j][l] = fmaf(a[j], w[l], acc[j][l]);
        }
    }

    // epilogue: single fp32 bias add per element, float4 stores
    const float4 b0 = *reinterpret_cast<const float4*>(&bias[n0 + tc * 8]);
    const float4 b1 = *reinterpret_cast<const float4*>(&bias[n0 + tc * 8 + 4]);
    const float bb[8] = {b0.x, b0.y, b0.z, b0.w, b1.x, b1.y, b1.z, b1.w};
#pragma unroll
    for (int j = 0; j < 16; ++j) {
        const int m = m0 + tr * 16 + j;
#pragma unroll
        for (int h = 0; h < 2; ++h) {
            float4 o4;
            o4.x = acc[j][h * 4 + 0] + bb[h * 4 + 0];
            o4.y = acc[j][h * 4 + 1] + bb[h * 4 + 1];
            o4.z = acc[j][h * 4 + 2] + bb[h * 4 + 2];
            o4.w = acc[j][h * 4 + 3] + bb[h * 4 + 3];
            *reinterpret_cast<float4*>(&I[(size_t)m * kOut + n0 + tc * 8 + h * 4]) = o4;
        }
    }
}

// ---------------------------------------------------------------------------
// LIF scan (fp32, exact op order), 4 elements per thread (float4 I/O):
//   t1 = v / 20; u = I - t1; v = v + u; s = v > 1; v = s ? 0 : v
// Iin may alias out (per-thread read-before-write on identical addresses).
// ---------------------------------------------------------------------------
__global__ __launch_bounds__(256)
void lif_scan_f32(const float* Iin, float* out)
{
    const int idx4 = (blockIdx.x * blockDim.x + threadIdx.x) * 4;
    if (idx4 >= kB * kOut) return;

    float v0 = 0.0f, v1 = 0.0f, v2 = 0.0f, v3 = 0.0f;
    for (int t = 0; t < kT; ++t) {
        const size_t off = (size_t)t * (kB * kOut) + idx4;
        const float4 Iv = *reinterpret_cast<const float4*>(&Iin[off]);
        float4 s4;

        { const float t1 = v0 / 20.0f; const float u = Iv.x - t1; v0 = v0 + u;
          const bool s = (v0 > 1.0f); s4.x = s ? 1.0f : 0.0f; if (s) v0 = 0.0f; }
        { const float t1 = v1 / 20.0f; const float u = Iv.y - t1; v1 = v1 + u;
          const bool s = (v1 > 1.0f); s4.y = s ? 1.0f : 0.0f; if (s) v1 = 0.0f; }
        { const float t1 = v2 / 20.0f; const float u = Iv.z - t1; v2 = v2 + u;
          const bool s = (v2 > 1.0f); s4.z = s ? 1.0f : 0.0f; if (s) v2 = 0.0f; }
        { const float t1 = v3 / 20.0f; const float u = Iv.w - t1; v3 = v3 + u;
          const bool s = (v3 > 1.0f); s4.w = s ? 1.0f : 0.0f; if (s) v3 = 0.0f; }

        *reinterpret_cast<float4*>(&out[off]) = s4;
    }
}

extern "C" void kernel_launch(void* const* d_in, const int* in_sizes, int n_in,
                              void* d_out, int out_size, void* d_ws, size_t ws_size,
                              hipStream_t stream) {
    const float* spikes = (const float*)d_in[0];   // [T, B, IN] fp32
    const float* W      = (const float*)d_in[1];   // [OUT, IN] fp32
    const float* bias   = (const float*)d_in[2];   // [OUT] fp32
    float* out = (float*)d_out;                    // [T, B, OUT] fp32 spikes

    const size_t iBytes = (size_t)kM * kOut * sizeof(float);   // 104.9 MB
    dim3 grid(kOut / BN, kM / BM);                 // 8 x 100

    float* Ibuf = (ws_size >= iBytes && d_ws != nullptr) ? (float*)d_ws : out;
    gemm_f32<<<grid, 256, 0, stream>>>(spikes, W, bias, Ibuf);
    lif_scan_f32<<<(kB * kOut) / (256 * 4), 256, 0, stream>>>(Ibuf, out);
}

// Round 5
// 678.867 us; speedup vs baseline: 1.2422x; 1.2422x over previous
//
#include <hip/hip_runtime.h>

// LIF layer: I = spikes @ W^T + b (fp32), then sequential fp32 LIF scan.
//
// NUMERICS CONTRACT (proven in round 2, absmax=0): each output element of the
// GEMM must be a strictly sequential ascending-k fmaf chain from 0.0f over
// k=0..1023, followed by exactly one fp32 bias add. The scan must be the exact
// op sequence t=v/20 (IEEE div); u=I-t; v=v+u; s=(v>1); v=s?0:v.
// Any blocking change must preserve the per-element rounding sequence.
//
// Round 5: round 4's 16x8 micro-tile spilled (VGPR capped at 128, WRITE_SIZE
// 102MB->411MB) and regressed. Revert to round 3's no-spill 8x8 structure
// (128x128x32, 660us) and keep only round 4's PROVEN win: the W chunk-XOR
// swizzle (conflicts 6.55e7 -> 3.3e6 measured). W k-rows store 16B chunk c at
// slot c^(c>>2): fragment reads and staging writes become 2-way (free);
// A reads were already broadcast/conflict-free.

constexpr int kT   = 100;
constexpr int kB   = 256;
constexpr int kIn  = 1024;
constexpr int kOut = 1024;
constexpr int kM   = kT * kB;          // 25600 GEMM rows

constexpr int BM = 128;
constexpr int BN = 128;
constexpr int BK = 32;

// ---------------------------------------------------------------------------
// GEMM: I[M,kOut] = A[M,kIn] * W^T[kOut,kIn] + bias   (fp32, sequential-k FMA)
// ---------------------------------------------------------------------------
__global__ __launch_bounds__(256, 3)
void gemm_f32(const float* __restrict__ A,
              const float* __restrict__ W,
              const float* __restrict__ bias,
              float* __restrict__ I)
{
    __shared__ float As[BK * BM];   // k-major: As[k*BM + m], linear
    __shared__ float Ws[BK * BN];   // k-major, 16B chunk c at slot c^(c>>2)

    const int tid = threadIdx.x;
    const int m0  = blockIdx.y * BM;
    const int n0  = blockIdx.x * BN;

    // compute mapping: 16x16 thread grid, 8x8 micro-tile each
    const int tc = tid & 15;
    const int tr = tid >> 4;

    // W-fragment read slots: thread reads chunks 2tc, 2tc+1 (floats tc*8..+7)
    const int pw0 = (((2 * tc    ) ^ ((2 * tc    ) >> 2)) & 31) * 4;
    const int pw1 = (((2 * tc + 1) ^ ((2 * tc + 1) >> 2)) & 31) * 4;

    // staging mapping: thread owns global row sr, k-half sc0 (0 or 16)
    const int sr  = tid >> 1;            // 0..127
    const int sc0 = (tid & 1) * 16;      // 0 or 16
    // W staging slot for row sr: chunk c=sr>>2 -> slot (c^(c>>2))*4 + (sr&3)
    const int wslot = ((((sr >> 2) ^ (sr >> 4)) & 31) * 4) + (sr & 3);

    const float* Arow = A + (size_t)(m0 + sr) * kIn + sc0;
    const float* Wrow = W + (size_t)(n0 + sr) * kIn + sc0;

    float4 la[4], lw[4];
#pragma unroll
    for (int i = 0; i < 4; ++i) {
        la[i] = *reinterpret_cast<const float4*>(Arow + i * 4);
        lw[i] = *reinterpret_cast<const float4*>(Wrow + i * 4);
    }

    float acc[8][8];
#pragma unroll
    for (int j = 0; j < 8; ++j)
#pragma unroll
        for (int l = 0; l < 8; ++l) acc[j][l] = 0.0f;

    for (int k0 = 0; k0 < kIn; k0 += BK) {
        __syncthreads();   // previous tile's compute done; LDS safe to overwrite

        // A writes: fixed (i,kk): 64 lanes -> 32 consecutive m each half: 2-way
        // W writes: permuted slots cover all 32 banks per 32-lane half: 2-way
#pragma unroll
        for (int i = 0; i < 4; ++i) {
            const float* lap = reinterpret_cast<const float*>(&la[i]);
            const float* lwp = reinterpret_cast<const float*>(&lw[i]);
#pragma unroll
            for (int kk = 0; kk < 4; ++kk) {
                const int k = sc0 + i * 4 + kk;
                As[k * BM + sr]    = lap[kk];
                Ws[k * BN + wslot] = lwp[kk];
            }
        }

        __syncthreads();

        // issue next tile's global loads now; they drain under the FMA phase
        if (k0 + BK < kIn) {
            const int kn = k0 + BK;
#pragma unroll
            for (int i = 0; i < 4; ++i) {
                la[i] = *reinterpret_cast<const float4*>(Arow + kn + i * 4);
                lw[i] = *reinterpret_cast<const float4*>(Wrow + kn + i * 4);
            }
        }

        // FMA phase: per k, 2 broadcast A-reads + 2 swizzled W-reads + 64 fmaf.
        // k strictly ascending => per-element chain order preserved.
#pragma unroll 2
        for (int k = 0; k < BK; ++k) {
            const float4 a0 = *reinterpret_cast<const float4*>(&As[k * BM + tr * 8]);
            const float4 a1 = *reinterpret_cast<const float4*>(&As[k * BM + tr * 8 + 4]);
            const float4 w0 = *reinterpret_cast<const float4*>(&Ws[k * BN + pw0]);
            const float4 w1 = *reinterpret_cast<const float4*>(&Ws[k * BN + pw1]);
            const float a[8] = {a0.x, a0.y, a0.z, a0.w, a1.x, a1.y, a1.z, a1.w};
            const float w[8] = {w0.x, w0.y, w0.z, w0.w, w1.x, w1.y, w1.z, w1.w};
#pragma unroll
            for (int j = 0; j < 8; ++j)
#pragma unroll
                for (int l = 0; l < 8; ++l)
                    acc[j][l] = fmaf(a[j], w[l], acc[j][l]);
        }
    }

    // epilogue: single fp32 bias add per element, float4 stores
#pragma unroll
    for (int j = 0; j < 8; ++j) {
        const int m = m0 + tr * 8 + j;
#pragma unroll
        for (int h = 0; h < 2; ++h) {
            const int n = n0 + tc * 8 + h * 4;
            float4 o4;
            o4.x = acc[j][h * 4 + 0] + bias[n + 0];
            o4.y = acc[j][h * 4 + 1] + bias[n + 1];
            o4.z = acc[j][h * 4 + 2] + bias[n + 2];
            o4.w = acc[j][h * 4 + 3] + bias[n + 3];
            *reinterpret_cast<float4*>(&I[(size_t)m * kOut + n]) = o4;
        }
    }
}

// ---------------------------------------------------------------------------
// LIF scan (fp32, exact op order), 4 elements per thread (float4 I/O):
//   t1 = v / 20; u = I - t1; v = v + u; s = v > 1; v = s ? 0 : v
// Iin may alias out (per-thread read-before-write on identical addresses).
// ---------------------------------------------------------------------------
__global__ __launch_bounds__(256)
void lif_scan_f32(const float* Iin, float* out)
{
    const int idx4 = (blockIdx.x * blockDim.x + threadIdx.x) * 4;
    if (idx4 >= kB * kOut) return;

    float v0 = 0.0f, v1 = 0.0f, v2 = 0.0f, v3 = 0.0f;
    for (int t = 0; t < kT; ++t) {
        const size_t off = (size_t)t * (kB * kOut) + idx4;
        const float4 Iv = *reinterpret_cast<const float4*>(&Iin[off]);
        float4 s4;

        { const float t1 = v0 / 20.0f; const float u = Iv.x - t1; v0 = v0 + u;
          const bool s = (v0 > 1.0f); s4.x = s ? 1.0f : 0.0f; if (s) v0 = 0.0f; }
        { const float t1 = v1 / 20.0f; const float u = Iv.y - t1; v1 = v1 + u;
          const bool s = (v1 > 1.0f); s4.y = s ? 1.0f : 0.0f; if (s) v1 = 0.0f; }
        { const float t1 = v2 / 20.0f; const float u = Iv.z - t1; v2 = v2 + u;
          const bool s = (v2 > 1.0f); s4.z = s ? 1.0f : 0.0f; if (s) v2 = 0.0f; }
        { const float t1 = v3 / 20.0f; const float u = Iv.w - t1; v3 = v3 + u;
          const bool s = (v3 > 1.0f); s4.w = s ? 1.0f : 0.0f; if (s) v3 = 0.0f; }

        *reinterpret_cast<float4*>(&out[off]) = s4;
    }
}

extern "C" void kernel_launch(void* const* d_in, const int* in_sizes, int n_in,
                              void* d_out, int out_size, void* d_ws, size_t ws_size,
                              hipStream_t stream) {
    const float* spikes = (const float*)d_in[0];   // [T, B, IN] fp32
    const float* W      = (const float*)d_in[1];   // [OUT, IN] fp32
    const float* bias   = (const float*)d_in[2];   // [OUT] fp32
    float* out = (float*)d_out;                    // [T, B, OUT] fp32 spikes

    const size_t iBytes = (size_t)kM * kOut * sizeof(float);   // 104.9 MB
    dim3 grid(kOut / BN, kM / BM);                 // 8 x 200

    float* Ibuf = (ws_size >= iBytes && d_ws != nullptr) ? (float*)d_ws : out;
    gemm_f32<<<grid, 256, 0, stream>>>(spikes, W, bias, Ibuf);
    lif_scan_f32<<<(kB * kOut) / (256 * 4), 256, 0, stream>>>(Ibuf, out);
}